// Round 1
// baseline (1005.751 us; speedup 1.0000x reference)
//
#include <hip/hip_runtime.h>
#include <math.h>

#define U_DIM 8192
#define P_DIM 4096
#define B_DIM 1024
#define H_DIM 50
#define EPSV  1e-8f

typedef __attribute__((ext_vector_type(8))) short short8;
typedef __attribute__((ext_vector_type(4))) float f32x4;

struct APtrs { const float* p[5]; };

__device__ inline unsigned short f2bf(float f) {
    unsigned int u = __float_as_uint(f);
    u += 0x7FFFu + ((u >> 16) & 1u);
    return (unsigned short)(u >> 16);
}

// ---------------------------------------------------------------------------
// Transpose + bf16 convert: in [K][64] fp32 -> out [64][K] bf16.
// Tiny (<= 2.6 MB outputs); runs once per B operand so the GEMM can read its
// B fragments as contiguous short8 directly from L2.
__global__ __launch_bounds__(256) void transpose_bf16_k(
    const float* __restrict__ in, unsigned short* __restrict__ out,
    int K, long strideIn, long strideOut)
{
    __shared__ float t[64][65];
    const int tid = threadIdx.x;
    const int kb  = blockIdx.x * 64;
    const float* ip = in + (size_t)blockIdx.y * strideIn + (size_t)kb * 64;
#pragma unroll
    for (int j = 0; j < 16; ++j) {
        int idx = tid + j * 256;
        t[idx >> 6][idx & 63] = ip[idx];
    }
    __syncthreads();
    unsigned short* op = out + (size_t)blockIdx.y * strideOut;
#pragma unroll
    for (int j = 0; j < 16; ++j) {
        int idx = tid + j * 256;
        int d = idx >> 6, k = idx & 63;
        op[(size_t)d * K + kb + k] = f2bf(t[k][d]);
    }
}

// ---------------------------------------------------------------------------
// C[M x 64] += op(A) @ B.  A fp32 streamed from HBM, B bf16-transposed [64][K].
// LDS-free / barrier-free: A has ZERO reuse in this problem, so each wave
// loads its own MFMA A-fragments directly from global (fragment layout
// row=lane&15, k=(lane>>4)*8+j coalesces in both orientations); B fragments
// are contiguous short8 reads from the L2-resident transposed copy.
// Ping-pong depth-1 pipeline, waves fully independent.
// TRANS=0: op(A)[m][k] = Ag[m*K + k]     (K = P_DIM, contraction over columns)
// TRANS=1: op(A)[m][k] = Ag[k*P_DIM + m] (K = U_DIM, contraction over rows)
template<bool TRANS>
__global__ __launch_bounds__(256, 4) void gemm_n64(
    APtrs Aps, const unsigned short* __restrict__ BT, float* __restrict__ C,
    long strideBT, long strideC, int kseg)
{
    const int K   = TRANS ? U_DIM : P_DIM;   // contraction length (compile-time)
    const int tid  = threadIdx.x;
    const int wid  = tid >> 6;
    const int lane = tid & 63;
    const int l15  = lane & 15;
    const int kg   = (lane >> 4) << 3;       // k-group offset 0/8/16/24
    const int m0   = blockIdx.x * 128 + wid * 32;  // wave's 32-row strip
    const float* Ag = Aps.p[blockIdx.y];
    const unsigned short* Bp = BT + (size_t)blockIdx.y * strideBT;
    float* Cp = C + (size_t)blockIdx.y * strideC;
    const long k0 = (long)blockIdx.z * kseg + kg;

    const float* a0;
    if (!TRANS) a0 = Ag + (size_t)(m0 + l15) * K + k0;
    else        a0 = Ag + (size_t)k0 * P_DIM + m0 + l15;
    const unsigned short* b0 = Bp + (size_t)l15 * K + k0;

    const size_t a16 = (size_t)16 * K;   // !TRANS: row m+16
    const size_t K16 = (size_t)16 * K;   // BT: 16 d-rows

    f32x4 acc[2][4] = {};

#define LOADA(A_, kk_) do {                                                     \
    if (!TRANS) {                                                               \
        const float* ap_ = a0 + (kk_);                                          \
        A_[0] = *(const float4*)ap_;          A_[1] = *(const float4*)(ap_ + 4);\
        A_[2] = *(const float4*)(ap_ + a16);  A_[3] = *(const float4*)(ap_ + a16 + 4); \
    } else {                                                                    \
        const float* ap_ = a0 + (size_t)(kk_) * P_DIM;                          \
        A_[0].x = ap_[0 * (size_t)P_DIM];      A_[0].y = ap_[1 * (size_t)P_DIM];\
        A_[0].z = ap_[2 * (size_t)P_DIM];      A_[0].w = ap_[3 * (size_t)P_DIM];\
        A_[1].x = ap_[4 * (size_t)P_DIM];      A_[1].y = ap_[5 * (size_t)P_DIM];\
        A_[1].z = ap_[6 * (size_t)P_DIM];      A_[1].w = ap_[7 * (size_t)P_DIM];\
        A_[2].x = ap_[0 * (size_t)P_DIM + 16]; A_[2].y = ap_[1 * (size_t)P_DIM + 16]; \
        A_[2].z = ap_[2 * (size_t)P_DIM + 16]; A_[2].w = ap_[3 * (size_t)P_DIM + 16]; \
        A_[3].x = ap_[4 * (size_t)P_DIM + 16]; A_[3].y = ap_[5 * (size_t)P_DIM + 16]; \
        A_[3].z = ap_[6 * (size_t)P_DIM + 16]; A_[3].w = ap_[7 * (size_t)P_DIM + 16]; \
    }                                                                           \
} while (0)

#define LOADB(B_, kk_) do {                                                     \
    B_[0] = *(const short8*)(b0 + (kk_));                                       \
    B_[1] = *(const short8*)(b0 + K16 + (kk_));                                 \
    B_[2] = *(const short8*)(b0 + 2 * K16 + (kk_));                             \
    B_[3] = *(const short8*)(b0 + 3 * K16 + (kk_));                             \
} while (0)

#define STEP(A_, B_) do {                                                       \
    short8 a0f, a1f;                                                            \
    a0f[0] = (short)f2bf(A_[0].x); a0f[1] = (short)f2bf(A_[0].y);               \
    a0f[2] = (short)f2bf(A_[0].z); a0f[3] = (short)f2bf(A_[0].w);               \
    a0f[4] = (short)f2bf(A_[1].x); a0f[5] = (short)f2bf(A_[1].y);               \
    a0f[6] = (short)f2bf(A_[1].z); a0f[7] = (short)f2bf(A_[1].w);               \
    a1f[0] = (short)f2bf(A_[2].x); a1f[1] = (short)f2bf(A_[2].y);               \
    a1f[2] = (short)f2bf(A_[2].z); a1f[3] = (short)f2bf(A_[2].w);               \
    a1f[4] = (short)f2bf(A_[3].x); a1f[5] = (short)f2bf(A_[3].y);               \
    a1f[6] = (short)f2bf(A_[3].z); a1f[7] = (short)f2bf(A_[3].w);               \
    _Pragma("unroll")                                                           \
    for (int nt = 0; nt < 4; ++nt) {                                            \
        acc[0][nt] = __builtin_amdgcn_mfma_f32_16x16x32_bf16(a0f, B_[nt], acc[0][nt], 0, 0, 0); \
        acc[1][nt] = __builtin_amdgcn_mfma_f32_16x16x32_bf16(a1f, B_[nt], acc[1][nt], 0, 0, 0); \
    }                                                                           \
} while (0)

    float4 Aa[4], Ab[4];
    short8 Ba[4], Bb[4];
    LOADA(Aa, 0); LOADB(Ba, 0);
    for (int kk = 0; kk < kseg; kk += 64) {
        LOADA(Ab, kk + 32); LOADB(Bb, kk + 32);   // next half in flight under STEP
        STEP(Aa, Ba);
        if (kk + 64 < kseg) { LOADA(Aa, kk + 64); LOADB(Ba, kk + 64); }
        STEP(Ab, Bb);
    }

#undef LOADA
#undef LOADB
#undef STEP

    // epilogue: atomic accumulate (C pre-zeroed; split-K partial sums)
    const int rb4 = (lane >> 4) << 2;
#pragma unroll
    for (int mt = 0; mt < 2; ++mt)
#pragma unroll
        for (int nt = 0; nt < 4; ++nt)
#pragma unroll
            for (int i = 0; i < 4; ++i) {
                int row = m0 + (mt << 4) + rb4 + i;
                atomicAdd(&Cp[((size_t)row << 6) + (nt << 4) + l15], acc[mt][nt][i]);
            }
}

__device__ inline float wsum(float v) {
#pragma unroll
    for (int off = 32; off > 0; off >>= 1) v += __shfl_xor(v, off, 64);
    return v;
}

// One wave per user: Xu, cosine sims vs base, mask/var, user_embedding.
__global__ __launch_bounds__(256) void user_stats_k(
    const float* __restrict__ u0, const float* __restrict__ u1,
    const float* __restrict__ u2, const float* __restrict__ W,
    float* __restrict__ base_o, float* __restrict__ var_o, float* __restrict__ ue_o)
{
    int u    = blockIdx.x * 4 + (threadIdx.x >> 6);
    int lane = threadIdx.x & 63;
    size_t ud = ((size_t)u << 6) + lane;

    float b0 = u0[ud];
    float xu[5];
#pragma unroll
    for (int r = 0; r < 5; ++r)
        xu[r] = (b0 + u1[(size_t)r * U_DIM * 64 + ud] + u2[(size_t)r * U_DIM * 64 + ud]) * (1.0f / 3.0f);

    float base = xu[0];
    float n0 = sqrtf(wsum(base * base));
    float sim[4];
#pragma unroll
    for (int a = 0; a < 4; ++a) {
        float d  = wsum(base * xu[a + 1]);
        float nr = sqrtf(wsum(xu[a + 1] * xu[a + 1]));
        sim[a] = d / fmaxf(n0 * nr, EPSV);
    }
    float smax = fmaxf(fmaxf(sim[0], sim[1]), fmaxf(sim[2], sim[3]));
    float ssum = 0.0f;
    float simm[4];
#pragma unroll
    for (int a = 0; a < 4; ++a) { simm[a] = (sim[a] == smax) ? sim[a] : 0.0f; ssum += simm[a]; }
    float mean = ssum * 0.25f;
    float vs = 0.0f;
#pragma unroll
    for (int a = 0; a < 4; ++a) { float t = simm[a] - mean; vs += t * t; }
    vs *= (1.0f / 3.0f);
    float var = logf(sqrtf(vs) + 1.0f);

    float ue = 0.0f;
#pragma unroll
    for (int a = 0; a < 4; ++a) ue += W[((size_t)u << 2) + a] * xu[a + 1];

    base_o[ud] = base;
    ue_o[ud]   = ue;
    if (lane == 0) var_o[u] = var;
}

// One wave per batch element: X_post, X_var_user, AugUser, X_mean_user.
__global__ __launch_bounds__(256) void gather_k(
    const float* __restrict__ p0, const float* __restrict__ p1r0, const float* __restrict__ p2,
    const float* __restrict__ base, const float* __restrict__ var, const float* __restrict__ ue,
    const int* __restrict__ src_id, const int* __restrict__ rumer, float* __restrict__ out)
{
    int b    = blockIdx.x * 4 + (threadIdx.x >> 6);
    int lane = threadIdx.x & 63;

    int sp = src_id[b];
    size_t spd = ((size_t)sp << 6) + lane;
    out[((size_t)b << 6) + lane] = (p0[spd] + p1r0[spd] + p2[spd]) * (1.0f / 3.0f);

    float xv = 0.0f, xm = 0.0f, au = 0.0f;
    for (int h = 0; h < H_DIM; ++h) {
        int uu = rumer[b * H_DIM + h];
        size_t uud = ((size_t)uu << 6) + lane;
        float bv = base[uud];
        xv += var[uu] * bv;
        xm += bv;
        au += ue[uud];
    }
    out[((size_t)(B_DIM     + b) << 6) + lane] = xv;
    out[((size_t)(2 * B_DIM + b) << 6) + lane] = au * (1.0f / H_DIM);
    out[((size_t)(3 * B_DIM + b) << 6) + lane] = xm * (1.0f / H_DIM);
}

extern "C" void kernel_launch(void* const* d_in, const int* in_sizes, int n_in,
                              void* d_out, int out_size, void* d_ws, size_t ws_size,
                              hipStream_t stream)
{
    const float* u0 = (const float*)d_in[5];
    const float* p0 = (const float*)d_in[6];
    const float* W  = (const float*)d_in[7];
    const int* src   = (const int*)d_in[8];
    const int* rumer = (const int*)d_in[10];
    float* out = (float*)d_out;

    APtrs Ap;
    for (int r = 0; r < 5; ++r) Ap.p[r] = (const float*)d_in[r];

    // workspace layout (fp32)
    float* u1   = (float*)d_ws;                 // 5*U*64
    float* p1   = u1 + 5l * U_DIM * 64;         // 5*P*64
    float* p2   = p1 + 5l * P_DIM * 64;         // P*64
    float* u2   = p2 + (long)P_DIM * 64;        // 5*U*64
    float* base = u2 + 5l * U_DIM * 64;         // U*64
    float* var  = base + (long)U_DIM * 64;      // U
    float* ue   = var + U_DIM;                  // U*64

    // bf16 transposed B-operand copies, ALIASED into base/var/ue (4.23 MB),
    // which user_stats_k only writes after all GEMMs are done.
    //   phase 1 (u1,p1 GEMMs):  p0T [64*P] then u0T [64*U]   (1.57 MB)
    //   phase 2 (u2,p2 GEMMs):  p1T [5*64*P] then u1T [64*U] (3.67 MB)
    unsigned short* p0T = (unsigned short*)base;
    unsigned short* u0T = p0T + 64l * P_DIM;
    unsigned short* p1T = (unsigned short*)base;        // reused after u0T is dead
    unsigned short* u1T = p1T + 5l * 64 * P_DIM;

    size_t zero_bytes = (size_t)(5l * U_DIM * 64 + 5l * P_DIM * 64 + (long)P_DIM * 64 + 5l * U_DIM * 64) * sizeof(float);
    hipMemsetAsync(d_ws, 0, zero_bytes, stream);

    // B-operand pre-transpose to bf16 [64][K]
    transpose_bf16_k<<<dim3(P_DIM / 64, 1), 256, 0, stream>>>(p0, p0T, P_DIM, 0, 0);
    transpose_bf16_k<<<dim3(U_DIM / 64, 1), 256, 0, stream>>>(u0, u0T, U_DIM, 0, 0);

    // u1[r] = A[r] @ p0          (K = P)
    gemm_n64<false><<<dim3(64, 5, 4), 256, 0, stream>>>(Ap, p0T, u1, 0, (long)U_DIM * 64, 1024);
    // p1[r] = A[r]^T @ u0        (K = U)
    gemm_n64<true ><<<dim3(32, 5, 8), 256, 0, stream>>>(Ap, u0T, p1, 0, (long)P_DIM * 64, 1024);

    transpose_bf16_k<<<dim3(P_DIM / 64, 5), 256, 0, stream>>>(p1, p1T, P_DIM, (long)P_DIM * 64, 64l * P_DIM);
    transpose_bf16_k<<<dim3(U_DIM / 64, 1), 256, 0, stream>>>(u1, u1T, U_DIM, 0, 0);

    // u2[r] = A[r] @ p1[r]
    gemm_n64<false><<<dim3(64, 5, 4), 256, 0, stream>>>(Ap, p1T, u2, 64l * P_DIM, (long)U_DIM * 64, 1024);
    // p2[0] = A[0]^T @ u1[0]
    gemm_n64<true ><<<dim3(32, 1, 32), 256, 0, stream>>>(Ap, u1T, p2, 0, 0, 256);

    user_stats_k<<<U_DIM / 4, 256, 0, stream>>>(u0, u1, u2, W, base, var, ue);
    gather_k<<<B_DIM / 4, 256, 0, stream>>>(p0, p1, p2, base, var, ue, src, rumer, out);
}